// Round 3
// baseline (232.529 us; speedup 1.0000x reference)
//
#include <hip/hip_runtime.h>
#include <stdint.h>

using f32x4  = __attribute__((ext_vector_type(4))) float;
using bf16x8 = __attribute__((ext_vector_type(8))) short;
using ushort8 = __attribute__((ext_vector_type(8))) unsigned short;

#define B_   16384
#define S_   256
#define DIN  2048
#define DFC  1024
#define NB_  10

// f32 -> bf16 round-to-nearest-even
__device__ __forceinline__ unsigned short f2bf(float f) {
  union { float f; unsigned int u; } v; v.f = f;
  unsigned int u = v.u;
  unsigned int r = (u + 0x7FFFu + ((u >> 16) & 1u)) >> 16;
  return (unsigned short)r;
}

// async global->LDS, 16B per lane. LDS dest is wave-uniform base + lane*16.
__device__ __forceinline__ void gload_lds16(const void* g, void* l) {
  __builtin_amdgcn_global_load_lds(
      (const __attribute__((address_space(1))) unsigned int*)g,
      (__attribute__((address_space(3))) unsigned int*)l, 16, 0, 0);
}

// ---------------- K0a: W1 (f32, [K=2048][N=1024]) -> Wt (bf16, [N][K]) ----------------
__global__ __launch_bounds__(256)
void convT_kernel(const float* __restrict__ W, unsigned short* __restrict__ Wt) {
  __shared__ unsigned short t[32][33];
  const int tx = threadIdx.x & 31;
  const int ty = threadIdx.x >> 5;          // 0..7
  const int nb = blockIdx.x * 32;           // n base
  const int kb = blockIdx.y * 32;           // k base
#pragma unroll
  for (int i = 0; i < 32; i += 8)
    t[ty + i][tx] = f2bf(W[(size_t)(kb + ty + i) * DFC + nb + tx]);
  __syncthreads();
#pragma unroll
  for (int i = 0; i < 32; i += 8)
    Wt[(size_t)(nb + ty + i) * DIN + kb + tx] = t[tx][ty + i];
}

// ---------------- K0b: A (f32 [16384][2048]) -> Ab (bf16, same layout) ----------------
__global__ __launch_bounds__(256)
void convA_kernel(const float* __restrict__ A, unsigned short* __restrict__ Ab) {
  const size_t total = (size_t)B_ * DIN;
  size_t idx = ((size_t)blockIdx.x * 256 + threadIdx.x) * 8;
  const size_t stride = (size_t)gridDim.x * 256 * 8;
  for (; idx < total; idx += stride) {
    f32x4 a = *(const f32x4*)(A + idx);
    f32x4 b = *(const f32x4*)(A + idx + 4);
    ushort8 o;
    o[0] = f2bf(a[0]); o[1] = f2bf(a[1]); o[2] = f2bf(a[2]); o[3] = f2bf(a[3]);
    o[4] = f2bf(b[0]); o[5] = f2bf(b[1]); o[6] = f2bf(b[2]); o[7] = f2bf(b[3]);
    *(ushort8*)(Ab + idx) = o;
  }
}

// ---------------- K1: x = elu(Ab @ Wt^T + b1), stored bf16 ----------------
// 256x256 tile, 8 waves (2M x 4N), BK=32, ring-of-4 LDS buffers, counted vmcnt,
// 4-phase per K-tile with setprio around MFMA clusters.
// LDS layout per tile: 128 "lrows" of 8 x 16B chunks (two tile-rows packed per
// lrow). Chunk at position p of lrow holds (row = lrow*2 + (p^lrow&7)>>2,
// kchunk = (p^lrow&7)&3) -> conflict-free ds_read_b128 (8x8 bijection/wave),
// staged via linear global_load_lds with inverse-swizzled global source.
__global__ __launch_bounds__(512, 2)
void gemm1_kernel(const unsigned short* __restrict__ Ab, const unsigned short* __restrict__ Bt,
                  const float* __restrict__ b1, unsigned short* __restrict__ X) {
  __shared__ unsigned short sA[4][8192];   // 4 bufs x 16KB = 64KB
  __shared__ unsigned short sB[4][8192];   // 64KB
  const int tid  = threadIdx.x;
  const int wave = tid >> 6, lane = tid & 63;
  const int wm = wave >> 2, wn = wave & 3;          // 2M x 4N waves
  // XCD-chunked bijective swizzle (256 blocks, 256%8==0)
  const int b = blockIdx.x;
  const int tile = (b & 7) * 32 + (b >> 3);
  const int mtile = tile >> 2, ntile = tile & 3;
  const int rowBase = mtile * 256, colBase = ntile * 256;

  f32x4 acc[8][4] = {};

  // ---- staging source mapping (per wave, 2 instrs per operand per K-tile) ----
  // chunk id = (wave*2+i)*64 + lane ; lrow = id>>3, p = lane&7
  const int lrow0 = wave * 16 + (lane >> 3);        // i=0 ; i=1 adds 8 (same &7)
  const int lchS  = (lane & 7) ^ (lrow0 & 7);
  const int Rs    = (lrow0 << 1) | (lchS >> 2);
  const int cs    = (lchS & 3) * 8;
  const unsigned short* gA0 = Ab + (size_t)(rowBase + Rs) * DIN + cs;
  const unsigned short* gA1 = gA0 + (size_t)16 * DIN;
  const unsigned short* gB0 = Bt + (size_t)(colBase + Rs) * DIN + cs;
  const unsigned short* gB1 = gB0 + (size_t)16 * DIN;
  const int ld0 = wave * 1024;                      // elem offset of instr 0 dest
  const int ld1 = wave * 1024 + 512;                // instr 1 dest

  // ---- fragment read offsets (constant across m/n/kt) ----
  const int frow = lane & 15, hi = lane >> 4;
  const int lch  = (((frow & 1) << 2) | hi) ^ ((frow >> 1) & 7);
  const int aoff = (wm * 64 + (frow >> 1)) * 64 + lch * 8;   // + m*512
  const int boff = (wn * 32 + (frow >> 1)) * 64 + lch * 8;   // + n*512

  // ---- prologue: stage K-tiles 0..2 into bufs 0..2 (12 loads/wave) ----
#pragma unroll
  for (int t = 0; t < 3; ++t) {
    gload_lds16(gA0 + t * 32, &sA[t][ld0]);
    gload_lds16(gA1 + t * 32, &sA[t][ld1]);
    gload_lds16(gB0 + t * 32, &sB[t][ld0]);
    gload_lds16(gB1 + t * 32, &sB[t][ld1]);
  }

#define DO_PHASE(P, STCODE)                                                                \
  {                                                                                        \
    bf16x8 a0 = *(const bf16x8*)&sAb[aoff + (2 * (P)) * 512];                              \
    bf16x8 a1 = *(const bf16x8*)&sAb[aoff + (2 * (P) + 1) * 512];                          \
    STCODE;                                                                                \
    __builtin_amdgcn_s_setprio(1);                                                         \
    acc[2*(P)][0]   = __builtin_amdgcn_mfma_f32_16x16x32_bf16(a0, bf0, acc[2*(P)][0],0,0,0);   \
    acc[2*(P)][1]   = __builtin_amdgcn_mfma_f32_16x16x32_bf16(a0, bf1, acc[2*(P)][1],0,0,0);   \
    acc[2*(P)][2]   = __builtin_amdgcn_mfma_f32_16x16x32_bf16(a0, bf2, acc[2*(P)][2],0,0,0);   \
    acc[2*(P)][3]   = __builtin_amdgcn_mfma_f32_16x16x32_bf16(a0, bf3, acc[2*(P)][3],0,0,0);   \
    acc[2*(P)+1][0] = __builtin_amdgcn_mfma_f32_16x16x32_bf16(a1, bf0, acc[2*(P)+1][0],0,0,0); \
    acc[2*(P)+1][1] = __builtin_amdgcn_mfma_f32_16x16x32_bf16(a1, bf1, acc[2*(P)+1][1],0,0,0); \
    acc[2*(P)+1][2] = __builtin_amdgcn_mfma_f32_16x16x32_bf16(a1, bf2, acc[2*(P)+1][2],0,0,0); \
    acc[2*(P)+1][3] = __builtin_amdgcn_mfma_f32_16x16x32_bf16(a1, bf3, acc[2*(P)+1][3],0,0,0); \
    __builtin_amdgcn_s_setprio(0);                                                         \
  }

  const int NT = DIN / 32;  // 64 K-tiles
  for (int t = 0; t < NT; ++t) {
    unsigned short* sAb = sA[t & 3];
    unsigned short* sBb = sB[t & 3];
    // counted vmcnt: tiles t+1, t+2 may stay in flight (4 loads each)
    if (t < NT - 2)       asm volatile("s_waitcnt vmcnt(8)" ::: "memory");
    else if (t == NT - 2) asm volatile("s_waitcnt vmcnt(4)" ::: "memory");
    else                  asm volatile("s_waitcnt vmcnt(0)" ::: "memory");
    __builtin_amdgcn_s_barrier();

    const bool st  = (t + 3) < NT;
    const int sbuf = (t + 3) & 3;
    const int skt  = (t + 3) * 32;

    bf16x8 bf0 = *(const bf16x8*)&sBb[boff];
    bf16x8 bf1 = *(const bf16x8*)&sBb[boff + 512];
    bf16x8 bf2 = *(const bf16x8*)&sBb[boff + 1024];
    bf16x8 bf3 = *(const bf16x8*)&sBb[boff + 1536];

    DO_PHASE(0, if (st) gload_lds16(gA0 + skt, &sA[sbuf][ld0]))
    __builtin_amdgcn_s_barrier();
    DO_PHASE(1, if (st) gload_lds16(gA1 + skt, &sA[sbuf][ld1]))
    __builtin_amdgcn_s_barrier();
    DO_PHASE(2, if (st) gload_lds16(gB0 + skt, &sB[sbuf][ld0]))
    __builtin_amdgcn_s_barrier();
    DO_PHASE(3, if (st) gload_lds16(gB1 + skt, &sB[sbuf][ld1]))
  }
#undef DO_PHASE

  // epilogue: C/D layout col = lane&15, row = (lane>>4)*4 + reg
  const int er0 = rowBase + wm * 128 + hi * 4;
  const int ec0 = colBase + wn * 64 + frow;
  float bv[4];
#pragma unroll
  for (int n = 0; n < 4; ++n) bv[n] = b1[ec0 + n * 16];
#pragma unroll
  for (int m = 0; m < 8; ++m)
#pragma unroll
    for (int n = 0; n < 4; ++n)
#pragma unroll
      for (int r = 0; r < 4; ++r) {
        float v = acc[m][n][r] + bv[n];
        v = v > 0.f ? v : expm1f(v);
        X[(size_t)(er0 + m * 16 + r) * DFC + ec0 + n * 16] = f2bf(v);
      }
}

// ---------------- K2: shape_params = x @ w_shape + b_shape -> d_out (mode | log_std) ----------------
__global__ __launch_bounds__(256)
void gemm2_kernel(const unsigned short* __restrict__ X, const float* __restrict__ Wsh,
                  const float* __restrict__ bsh, float* __restrict__ out) {
  __shared__ unsigned short sX[64 * 32];    // linear for global_load_lds
  __shared__ unsigned short sW[32 * 40];    // [j][k] stride 40 (80B)
  const int tid  = threadIdx.x;
  const int wave = tid >> 6, lane = tid & 63;
  const int rowB = blockIdx.x * 64;
  f32x4 acc[2] = {};
  const unsigned short* xp = X + (size_t)(rowB + (tid >> 2)) * DFC + (tid & 3) * 8;
  unsigned short* sXb = &sX[wave * 512];
  const int frow = lane & 15, fks = (lane >> 4) * 8;

  for (int kk = 0; kk < DFC; kk += 32) {
    gload_lds16(xp + kk, sXb);
    for (int idx = tid; idx < 32 * 40; idx += 256) {
      int j = idx / 40, ki = idx - j * 40;
      sW[idx] = (j < 20 && ki < 32) ? f2bf(Wsh[(size_t)(kk + ki) * 20 + j]) : (unsigned short)0;
    }
    __syncthreads();
    bf16x8 xa  = *(const bf16x8*)&sX[(wave * 16 + frow) * 32 + fks];
    bf16x8 w0  = *(const bf16x8*)&sW[(frow) * 40 + fks];
    bf16x8 w1f = *(const bf16x8*)&sW[(16 + frow) * 40 + fks];
    acc[0] = __builtin_amdgcn_mfma_f32_16x16x32_bf16(xa, w0,  acc[0], 0, 0, 0);
    acc[1] = __builtin_amdgcn_mfma_f32_16x16x32_bf16(xa, w1f, acc[1], 0, 0, 0);
    __syncthreads();
  }
  const int r0 = rowB + wave * 16 + (lane >> 4) * 4;
  const int c0 = lane & 15;
#pragma unroll
  for (int n = 0; n < 2; ++n) {
    int j = n * 16 + c0;
    if (j < 20) {
      float bj = bsh[j];
      int jj = j < 10 ? j : j - 10;
      size_t base = (j < 10) ? (size_t)0 : (size_t)B_ * NB_;
#pragma unroll
      for (int r = 0; r < 4; ++r)
        out[base + (size_t)(r0 + r) * NB_ + jj] = acc[n][r] + bj;
    }
  }
}

// ---------------- K3: samples = mode + exp(log_std) * noise ----------------
__global__ __launch_bounds__(256)
void sample_kernel(const float* __restrict__ noise, float* __restrict__ out) {
  __shared__ float sm[4][NB_], se[4][NB_];
  const int tid  = threadIdx.x;
  const int wave = tid >> 6, lane = tid & 63;
  const int row  = blockIdx.x * 4 + wave;
  if (lane < NB_) {
    sm[wave][lane] = out[(size_t)row * NB_ + lane];
    se[wave][lane] = expf(out[(size_t)B_ * NB_ + (size_t)row * NB_ + lane]);
  }
  __syncthreads();
  const f32x4* np4 = (const f32x4*)(noise + (size_t)row * (S_ * NB_));
  f32x4*       op4 = (f32x4*)(out + (size_t)2 * B_ * NB_ + (size_t)row * (S_ * NB_));
#pragma unroll
  for (int it = 0; it < (S_ * NB_) / 256; ++it) {   // 10 iters
    f32x4 nv = np4[it * 64 + lane];
    int j0 = (lane * 4 + it * 6) % 10;
    int j1 = j0 + 1; if (j1 >= 10) j1 -= 10;
    int j2 = j1 + 1; if (j2 >= 10) j2 -= 10;
    int j3 = j2 + 1; if (j3 >= 10) j3 -= 10;
    f32x4 r;
    r[0] = sm[wave][j0] + se[wave][j0] * nv[0];
    r[1] = sm[wave][j1] + se[wave][j1] * nv[1];
    r[2] = sm[wave][j2] + se[wave][j2] * nv[2];
    r[3] = sm[wave][j3] + se[wave][j3] * nv[3];
    op4[it * 64 + lane] = r;
  }
}

extern "C" void kernel_launch(void* const* d_in, const int* in_sizes, int n_in,
                              void* d_out, int out_size, void* d_ws, size_t ws_size,
                              hipStream_t stream) {
  const float* A     = (const float*)d_in[0];  // [16384][2048]
  const float* W1    = (const float*)d_in[1];  // [2048][1024]
  const float* b1    = (const float*)d_in[2];  // [1024]
  const float* Wsh   = (const float*)d_in[3];  // [1024][20]
  const float* bsh   = (const float*)d_in[4];  // [20]
  const float* noise = (const float*)d_in[5];  // [16384][256][10]
  float* out = (float*)d_out;                  // mode | log_std | samples

  unsigned short* Wt = (unsigned short*)d_ws;                      // bf16 [1024][2048] = 4 MB
  unsigned short* X  = (unsigned short*)d_ws + (size_t)DFC * DIN;  // bf16 [16384][1024] = 33.5 MB
  // Ab (bf16 A, 64 MB): ws if it fits, else stash in d_out's samples region
  // (written before gemm1 reads it, overwritten by sample_kernel at the end).
  const size_t wsNeed = (size_t)DFC * DIN * 2 + (size_t)B_ * DFC * 2 + (size_t)B_ * DIN * 2;
  unsigned short* Ab = (ws_size >= wsNeed)
      ? (unsigned short*)d_ws + (size_t)DFC * DIN + (size_t)B_ * DFC
      : (unsigned short*)(out + (size_t)2 * B_ * NB_);

  convT_kernel<<<dim3(DFC / 32, DIN / 32), 256, 0, stream>>>(W1, Wt);
  convA_kernel<<<dim3(2048), 256, 0, stream>>>(A, Ab);
  gemm1_kernel<<<dim3((B_ / 256) * (DFC / 256)), 512, 0, stream>>>(Ab, Wt, b1, X);
  gemm2_kernel<<<dim3(B_ / 64), 256, 0, stream>>>(X, Wsh, bsh, out);
  sample_kernel<<<dim3(B_ / 4), 256, 0, stream>>>(noise, out);
}